// Round 5
// baseline (683.499 us; speedup 1.0000x reference)
//
#include <hip/hip_runtime.h>
#include <math.h>
#include <cstddef>

// Problem constants
#define H 256
#define NH 8
#define DH 32
#define LAYERS 2
#define BB 32
#define SS 512
#define FINDIM 199
#define AA 4
#define T_TOK (BB*SS)   // 16384 tokens
#define KIN 224         // padded input K (199 x + 3 tf + 22 zero)

typedef unsigned short u16;
typedef unsigned int u32;
typedef __attribute__((ext_vector_type(8))) short short8;  // 8 bf16 (4 VGPRs)
typedef __attribute__((ext_vector_type(4))) float f4;      // MFMA C/D

__device__ __forceinline__ float b2f(u16 v){
  unsigned u = ((unsigned)v) << 16;
  return __builtin_bit_cast(float, u);
}
__device__ __forceinline__ u16 f2b(float f){
  unsigned u = __builtin_bit_cast(unsigned, f);
  unsigned r = (u + 0x7fffu + ((u >> 16) & 1u)) >> 16;   // RNE
  return (u16)r;
}
__device__ __forceinline__ float wave_sum(float v){
  #pragma unroll
  for (int mk=1; mk<64; mk<<=1) v += __shfl_xor(v, mk, 64);
  return v;
}

#define GLD_LDS16(g, l) \
  __builtin_amdgcn_global_load_lds((const __attribute__((address_space(1))) void*)(g), \
                                   (__attribute__((address_space(3))) void*)(l), 16, 0, 0)

#define SA (KIN+8)   // 232
#define SY (H+8)     // 264

// =========================================================================
// MFMA stage primitives (512-thread block, 32 tokens, full N=256;
// wave w owns cols [32w,32w+32)).
// =========================================================================
template<int KC, int WK>
__device__ __forceinline__ void stage_acc(
    const u16* Xl, int sx, const u16* __restrict__ Wt,
    int c0, int l16, int lq, f4 acc[2][2])
{
  #pragma unroll
  for (int mi=0;mi<2;mi++)
    #pragma unroll
    for (int ni=0;ni<2;ni++) acc[mi][ni] = (f4){0.f,0.f,0.f,0.f};
  #pragma unroll
  for (int kc=0;kc<KC;kc++){
    short8 af[2], bf[2];
    af[0] = *(const short8*)&Xl[(l16)*sx      + kc*32 + lq*8];
    af[1] = *(const short8*)&Xl[(16+l16)*sx   + kc*32 + lq*8];
    bf[0] = *(const short8*)(Wt + (size_t)(c0+l16)*WK    + kc*32 + lq*8);
    bf[1] = *(const short8*)(Wt + (size_t)(c0+16+l16)*WK + kc*32 + lq*8);
    #pragma unroll
    for (int mi=0;mi<2;mi++)
      #pragma unroll
      for (int ni=0;ni<2;ni++)
        acc[mi][ni] = __builtin_amdgcn_mfma_f32_16x16x32_bf16(af[mi], bf[ni], acc[mi][ni], 0,0,0);
  }
}

template<int DO_ELU>
__device__ __forceinline__ void stage_store(
    f4 acc[2][2], const float* __restrict__ bias,
    int c0, int l16, int lq, u16* Yl, int sy)
{
  #pragma unroll
  for (int ni=0;ni<2;ni++){
    int col = c0 + ni*16 + l16;
    float bc = bias[col];
    #pragma unroll
    for (int mi=0;mi<2;mi++){
      #pragma unroll
      for (int r=0;r<4;r++){
        int row = mi*16 + lq*4 + r;
        float v = acc[mi][ni][r] + bc;
        if (DO_ELU) v = v > 0.f ? v : (__expf(v) - 1.0f);
        Yl[row*sy + col] = f2b(v);
      }
    }
  }
}

__device__ __forceinline__ void tile_load256(const u16* g, u16* Yl, int sy, int t){
  #pragma unroll
  for (int j=0;j<2;j++){
    int u = t + j*512;
    int row = u >> 5, cu = u & 31;
    *(short8*)&Yl[row*sy + cu*8] = *(const short8*)(g + (size_t)row*H + cu*8);
  }
}

// LN over LDS tile rows; TO_LDS=1 writes bf16 LDS (stride SY), else global (stride H)
template<int TO_LDS>
__device__ __forceinline__ void tile_ln(
    const u16* Yl, int sy, const float* __restrict__ g, const float* __restrict__ b,
    u16* dst, int t)
{
  int w = t >> 6, lane = t & 63;
  #pragma unroll
  for (int rr=0;rr<4;rr++){
    int row = w*4 + rr;
    float xv[4];
    #pragma unroll
    for (int j=0;j<4;j++) xv[j] = b2f(Yl[row*sy + lane*4 + j]);
    float s=0.f, ss=0.f;
    #pragma unroll
    for (int j=0;j<4;j++){ s += xv[j]; ss += xv[j]*xv[j]; }
    s = wave_sum(s); ss = wave_sum(ss);
    float mean = s * (1.0f/H);
    float var  = ss * (1.0f/H) - mean*mean;
    float rstd = rsqrtf(var + 1e-5f);
    ushort4 o;
    int col = lane*4;
    o.x = f2b((xv[0]-mean)*rstd*g[col+0] + b[col+0]);
    o.y = f2b((xv[1]-mean)*rstd*g[col+1] + b[col+1]);
    o.z = f2b((xv[2]-mean)*rstd*g[col+2] + b[col+2]);
    o.w = f2b((xv[3]-mean)*rstd*g[col+3] + b[col+3]);
    if (TO_LDS) *(ushort4*)(dst + (size_t)row*SY + col) = o;
    else        *(ushort4*)(dst + (size_t)row*H  + col) = o;
  }
}

// =========================================================================
// prep_kernel: merged wconv (336 blocks) | wcat (224) | xconv (14336)
// =========================================================================
struct WPtrs { const float* p[21]; };

__global__ __launch_bounds__(256) void prep_kernel(
    WPtrs wp, u16* __restrict__ wts,
    const float* __restrict__ fp_w, const float* __restrict__ tp_w,
    u16* __restrict__ wcat,
    const float* __restrict__ x, const float* __restrict__ tf,
    u16* __restrict__ abuf){
  int bid = blockIdx.x;
  int t = threadIdx.x;
  if (bid < 336){
    __shared__ float tl[64][65];
    int mb = bid >> 4, tile = bid & 15;
    int k0 = (tile >> 2) * 64, n0 = (tile & 3) * 64;
    const float* src = wp.p[mb];
    int r = t >> 4, cg = t & 15;
    #pragma unroll
    for (int p4=0;p4<4;p4++){
      f4 v = *(const f4*)(src + (size_t)(k0 + r + p4*16)*H + n0 + cg*4);
      tl[r+p4*16][cg*4+0]=v[0]; tl[r+p4*16][cg*4+1]=v[1];
      tl[r+p4*16][cg*4+2]=v[2]; tl[r+p4*16][cg*4+3]=v[3];
    }
    __syncthreads();
    u16* db = wts + (size_t)mb*H*H;
    #pragma unroll
    for (int p4=0;p4<4;p4++){
      int rn = r + p4*16;
      ushort4 o;
      o.x = f2b(tl[cg*4+0][rn]); o.y = f2b(tl[cg*4+1][rn]);
      o.z = f2b(tl[cg*4+2][rn]); o.w = f2b(tl[cg*4+3][rn]);
      *(ushort4*)(db + (size_t)(n0+rn)*H + k0 + cg*4) = o;
    }
  } else if (bid < 336+224){
    int idx = (bid-336)*256 + t;       // n*224 + k
    int n = idx / KIN, k2 = idx % KIN;
    float v = 0.f;
    if (k2 < FINDIM) v = fp_w[(size_t)k2*H + n];
    else if (k2 < FINDIM+3) v = tp_w[(size_t)(k2-FINDIM)*H + n];
    wcat[idx] = f2b(v);
  } else {
    size_t idx = (size_t)(bid-560)*256 + t;   // tok*224 + k
    int tok = idx / KIN, k2 = idx % KIN;
    float v = 0.f;
    if (k2 < FINDIM) v = x[(size_t)tok*FINDIM + k2];
    else if (k2 < FINDIM+3) v = tf[(size_t)tok*3 + (k2-FINDIM)];
    abuf[idx] = f2b(v);
  }
}

// =========================================================================
// input_kernel: hid = (Abuf@Wcat^T + (fp_b+tp_b)) @ ip_w + ip_b + PE
// =========================================================================
__global__ __launch_bounds__(512, 4) void input_kernel(
    const u16* __restrict__ ab, const u16* __restrict__ wcat,
    const float* __restrict__ fp_b, const float* __restrict__ tp_b,
    const u16* __restrict__ ipw, const float* __restrict__ ip_b,
    u16* __restrict__ hid){
  __shared__ u16 Al[32*SA];
  __shared__ u16 Tl[32*SY];
  int t = threadIdx.x;
  int tok0 = blockIdx.x * 32;
  int lane = t & 63, w = t >> 6;
  int l16 = lane & 15, lq = lane >> 4;
  int c0 = w * 32;

  #pragma unroll
  for (int j=0;j<2;j++){
    int u = t + j*512;
    if (u < 896){
      int row = u / 28, cu = u % 28;
      *(short8*)&Al[row*SA + cu*8] = *(const short8*)(ab + (size_t)(tok0+row)*KIN + cu*8);
    }
  }
  __syncthreads();

  f4 acc[2][2];
  stage_acc<7, KIN>(Al, SA, wcat, c0, l16, lq, acc);
  #pragma unroll
  for (int ni=0;ni<2;ni++){
    int col = c0 + ni*16 + l16;
    float bc = fp_b[col] + tp_b[col];
    #pragma unroll
    for (int mi=0;mi<2;mi++)
      #pragma unroll
      for (int r=0;r<4;r++){
        int row = mi*16 + lq*4 + r;
        Tl[row*SY + col] = f2b(acc[mi][ni][r] + bc);
      }
  }
  __syncthreads();

  stage_acc<8, H>(Tl, SY, ipw, c0, l16, lq, acc);
  #pragma unroll
  for (int ni=0;ni<2;ni++){
    int col = c0 + ni*16 + l16;
    float bc = ip_b[col];
    int ii = col >> 1;
    float div = __expf((float)(2*ii) * -0.03597789207803197f);
    #pragma unroll
    for (int mi=0;mi<2;mi++)
      #pragma unroll
      for (int r=0;r<4;r++){
        int row = mi*16 + lq*4 + r;
        int s = (tok0 + row) & (SS-1);
        float arg = (float)s * div;
        float pe = (col & 1) ? __cosf(arg) : __sinf(arg);
        hid[(size_t)(tok0+row)*H + col] = f2b(acc[mi][ni][r] + bc + pe);
      }
  }
}

// =========================================================================
// post_kernel<WITH_OPROJ>: [oproj + residual-LN] + full GRN, 32 tokens/block.
//   WITH_OPROJ=1: x = LN(hid + ctx@wo + bo); hid_out = GRN(x)
//   WITH_OPROJ=0: x = hid;                   hid_out = GRN(x)
// =========================================================================
template<int WITH_OPROJ>
__global__ __launch_bounds__(512, 4) void post_kernel(
    const u16* __restrict__ ctx, u16* __restrict__ hid,
    const u16* __restrict__ wo, const float* __restrict__ bo,
    const float* __restrict__ lng, const float* __restrict__ lnb,
    const u16* __restrict__ fc1, const u16* __restrict__ fc2,
    const u16* __restrict__ gw,  const u16* __restrict__ ggw,
    const float* __restrict__ b1, const float* __restrict__ b2,
    const float* __restrict__ gb, const float* __restrict__ ggb,
    const float* __restrict__ lg, const float* __restrict__ lb){
  __shared__ u16 Xl[32*SY];
  __shared__ u16 Rl[32*SY];
  __shared__ u16 H1[32*SY];
  int t = threadIdx.x;
  int tok0 = blockIdx.x * 32;
  int lane = t & 63, w = t >> 6;
  int l16 = lane & 15, lq = lane >> 4;
  int c0 = w * 32;
  u16* hb = hid + (size_t)tok0*H;
  f4 acc[2][2];

  if (WITH_OPROJ){
    tile_load256(ctx + (size_t)tok0*H, Xl, SY, t);
    tile_load256(hb, Rl, SY, t);
    __syncthreads();
    stage_acc<8, H>(Xl, SY, wo, c0, l16, lq, acc);
    __syncthreads();                 // Xl reads done
    #pragma unroll
    for (int ni=0;ni<2;ni++){
      int col = c0 + ni*16 + l16;
      float bc = bo[col];
      #pragma unroll
      for (int mi=0;mi<2;mi++)
        #pragma unroll
        for (int r=0;r<4;r++){
          int row = mi*16 + lq*4 + r;
          Xl[row*SY + col] = f2b(acc[mi][ni][r] + bc + b2f(Rl[row*SY + col]));
        }
    }
    __syncthreads();
    tile_ln<1>(Xl, SY, lng, lnb, Rl, t);   // Rl = x (post-LN residual)
    __syncthreads();
  } else {
    tile_load256(hb, Rl, SY, t);           // Rl = x
    __syncthreads();
  }

  // GRN
  stage_acc<8, H>(Rl, SY, fc1, c0, l16, lq, acc);
  stage_store<1>(acc, b1, c0, l16, lq, Xl, SY);       // h1 -> Xl
  __syncthreads();
  stage_acc<8, H>(Xl, SY, fc2, c0, l16, lq, acc);
  stage_store<1>(acc, b2, c0, l16, lq, H1, SY);       // h2 -> H1
  __syncthreads();
  stage_acc<8, H>(H1, SY, gw, c0, l16, lq, acc);
  stage_store<0>(acc, gb, c0, l16, lq, Xl, SY);       // g  -> Xl
  __syncthreads();
  stage_acc<8, H>(H1, SY, ggw, c0, l16, lq, acc);     // gg in acc
  __syncthreads();                                    // H1 reads done
  #pragma unroll
  for (int ni=0;ni<2;ni++){
    int col = c0 + ni*16 + l16;
    float bc = ggb[col];
    #pragma unroll
    for (int mi=0;mi<2;mi++)
      #pragma unroll
      for (int r=0;r<4;r++){
        int row = mi*16 + lq*4 + r;
        float gg = acc[mi][ni][r] + bc;
        float sg = 1.0f/(1.0f + __expf(-gg));
        float y  = b2f(Xl[row*SY + col]) * sg + b2f(Rl[row*SY + col]);
        H1[row*SY + col] = f2b(y);
      }
  }
  __syncthreads();
  tile_ln<0>(H1, SY, lg, lb, hb, t);
}

// =========================================================================
// QKV GEMM: 128x64 tile, global_load_lds, z-batched over 3 jobs.
// =========================================================================
struct GemmJob  { const u16* Wt; const float* bias; u16* C; };
struct GemmBatch{ GemmJob j[3]; };

__global__ __launch_bounds__(256) void gemm_bf16(
    const u16* __restrict__ A, GemmBatch jb) {
  __shared__ u16 smem[128*64 + 64*64];
  u16* As  = smem;
  u16* Wsm = smem + 128*64;
  const GemmJob job = jb.j[blockIdx.z];
  const u16* Wt = job.Wt;
  int t = threadIdx.x;
  int m0 = blockIdx.x * 128;
  int n0 = blockIdx.y * 64;
  int lane = t & 63, w = t >> 6;
  int wr = (w >> 1) * 64;
  int wc = (w & 1) * 32;
  int l16 = lane & 15, lq = lane >> 4;

  f4 acc[4][2];
  #pragma unroll
  for (int mi=0;mi<4;mi++)
    #pragma unroll
    for (int ni=0;ni<2;ni++) acc[mi][ni] = (f4){0.f,0.f,0.f,0.f};

  for (int k0=0;k0<256;k0+=64){
    #pragma unroll
    for (int ja=0;ja<4;ja++){
      int ub = (w*4 + ja)*64;
      int u  = ub + lane;
      int m  = u >> 3, c = u & 7, kx = c ^ (m & 7);
      const u16* g = A + (size_t)(m0+m)*H + k0 + kx*8;
      GLD_LDS16(g, As + (size_t)ub*8);
    }
    #pragma unroll
    for (int jb2=0;jb2<2;jb2++){
      int ub = (w*2 + jb2)*64;
      int u  = ub + lane;
      int n  = u >> 3, c = u & 7, kx = c ^ (n & 7);
      const u16* g = Wt + (size_t)(n0+n)*H + k0 + kx*8;
      GLD_LDS16(g, Wsm + (size_t)ub*8);
    }
    __syncthreads();
    #pragma unroll
    for (int kc=0;kc<2;kc++){
      short8 af[4], bf[2];
      int kx = kc*4 + lq;
      #pragma unroll
      for (int mi=0;mi<4;mi++){
        int m = wr + mi*16 + l16;
        int un = (m<<3) | (kx ^ (m&7));
        af[mi] = *(short8*)&As[un*8];
      }
      #pragma unroll
      for (int ni=0;ni<2;ni++){
        int n = wc + ni*16 + l16;
        int un = (n<<3) | (kx ^ (n&7));
        bf[ni] = *(short8*)&Wsm[un*8];
      }
      #pragma unroll
      for (int mi=0;mi<4;mi++)
        #pragma unroll
        for (int ni=0;ni<2;ni++)
          acc[mi][ni] = __builtin_amdgcn_mfma_f32_16x16x32_bf16(af[mi], bf[ni], acc[mi][ni], 0,0,0);
    }
    __syncthreads();
  }

  u16* Cl = smem;
  #pragma unroll
  for (int ni=0;ni<2;ni++){
    int coll = wc + ni*16 + l16;
    float bcol = job.bias[n0 + coll];
    #pragma unroll
    for (int mi=0;mi<4;mi++){
      #pragma unroll
      for (int r=0;r<4;r++){
        int rowl = wr + mi*16 + lq*4 + r;
        Cl[rowl*68 + coll] = f2b(acc[mi][ni][r] + bcol);
      }
    }
  }
  __syncthreads();
  #pragma unroll
  for (int q2=0;q2<4;q2++){
    int u = q2*256 + t;
    int row = u >> 3, cu = u & 7;
    short8 val = *(short8*)&Cl[row*68 + cu*8];
    *(short8*)(job.C + (size_t)(m0+row)*H + n0 + cu*8) = val;
  }
}

// =========================================================================
// Fused causal attention. aw stores (WRITE_AW) go through per-wave LDS
// transpose -> float4 stores with 16 lanes x 16 B = 256 B contiguous.
// =========================================================================
template<int WRITE_AW>
__global__ __launch_bounds__(256) void attn_kernel(
    const u16* __restrict__ q, const u16* __restrict__ k,
    const u16* __restrict__ v, float* __restrict__ aw,
    u16* __restrict__ ctx) {
  __shared__ u16 Vt[DH][SS+8];
  __shared__ u16 Plds[4][16][72];
  int t  = threadIdx.x;
  int zg = blockIdx.x;
  int bh = blockIdx.y;
  int b  = bh >> 3, h = bh & 7;
  int lane = t & 63, w = t >> 6;
  int l16 = lane & 15, lq = lane >> 4;
  const float scale = 0.17677669529663687f;

  #pragma unroll
  for (int rep=0;rep<2;rep++){
    int kk = t + rep*256;
    const u16* vp = v + ((size_t)(b*SS + kk))*H + h*DH;
    short8 r0 = *(const short8*)(vp);
    short8 r1 = *(const short8*)(vp+8);
    short8 r2 = *(const short8*)(vp+16);
    short8 r3 = *(const short8*)(vp+24);
    #pragma unroll
    for (int j=0;j<8;j++){
      Vt[j][kk]    = (u16)r0[j];
      Vt[8+j][kk]  = (u16)r1[j];
      Vt[16+j][kk] = (u16)r2[j];
      Vt[24+j][kk] = (u16)r3[j];
    }
  }
  __syncthreads();

  for (int it=0; it<4; it++){
    int qt  = zg + it*2;
    int qr0 = qt*64 + w*16;
    int KT  = qt*4 + w + 1;
    short8 af = *(const short8*)(q + ((size_t)(b*SS + qr0 + l16))*H + h*DH + lq*8);

    float l[4] = {0.f,0.f,0.f,0.f};
    f4 o[2] = {(f4){0.f,0.f,0.f,0.f}, (f4){0.f,0.f,0.f,0.f}};
    u32 pk0[32], pk1[32];

    #pragma unroll
    for (int c8=0;c8<8;c8++){
      if (c8*4 < KT){
        #pragma unroll
        for (int j=0;j<4;j++){
          int kt = c8*4 + j;
          float p[4] = {0.f,0.f,0.f,0.f};
          if (kt < KT){
            short8 bfr = *(const short8*)(k + ((size_t)(b*SS + kt*16 + l16))*H + h*DH + lq*8);
            f4 cc = (f4){0.f,0.f,0.f,0.f};
            cc = __builtin_amdgcn_mfma_f32_16x16x32_bf16(af, bfr, cc, 0,0,0);
            int col = kt*16 + l16;
            #pragma unroll
            for (int i=0;i<4;i++){
              int qi = qr0 + lq*4 + i;
              float sc = (col <= qi) ? cc[i]*scale : -3.0e38f;
              p[i] = __expf(sc);          // masked -> exactly 0
              l[i] += p[i];
            }
          }
          u16 pb[4];
          #pragma unroll
          for (int i=0;i<4;i++) pb[i] = f2b(p[i]);
          if (WRITE_AW){
            pk0[kt] = (u32)pb[0] | ((u32)pb[1] << 16);
            pk1[kt] = (u32)pb[2] | ((u32)pb[3] << 16);
          }
          #pragma unroll
          for (int i=0;i<4;i++) Plds[w][lq*4+i][j*16+l16] = pb[i];
        }
        #pragma unroll
        for (int kc=0;kc<2;kc++){
          short8 pa = *(short8*)&Plds[w][l16][kc*32 + lq*8];
          #pragma unroll
          for (int dt=0;dt<2;dt++){
            short8 vb = *(const short8*)&Vt[dt*16 + l16][c8*64 + kc*32 + lq*8];
            o[dt] = __builtin_amdgcn_mfma_f32_16x16x32_bf16(pa, vb, o[dt], 0,0,0);
          }
        }
      }
    }

    #pragma unroll
    for (int i=0;i<4;i++){
      #pragma unroll
      for (int mk=1; mk<16; mk<<=1) l[i] += __shfl_xor(l[i], mk, 64);
    }
    float inv[4];
    #pragma unroll
    for (int i=0;i<4;i++) inv[i] = 1.0f / l[i];

    if (WRITE_AW){
      float* ab = aw + (size_t)bh*SS*SS;
      #pragma unroll
      for (int c8=0;c8<8;c8++){
        int cbase = c8*64;
        if (c8*4 < KT){
          // normalized p -> per-wave LDS transpose
          #pragma unroll
          for (int j=0;j<4;j++){
            int kt = c8*4 + j;
            float pv[4] = {0.f,0.f,0.f,0.f};
            if (kt < KT){
              pv[0]=b2f((u16)pk0[kt]); pv[1]=b2f((u16)(pk0[kt]>>16));
              pv[2]=b2f((u16)pk1[kt]); pv[3]=b2f((u16)(pk1[kt]>>16));
            }
            #pragma unroll
            for (int i=0;i<4;i++) Plds[w][lq*4+i][j*16+l16] = f2b(pv[i]*inv[i]);
          }
          // 16 lanes cover 256 B contiguous per row
          #pragma unroll
          for (int r4=0;r4<4;r4++){
            int row = r4*4 + lq;
            float4 o4;
            o4.x = b2f(Plds[w][row][l16*4+0]);
            o4.y = b2f(Plds[w][row][l16*4+1]);
            o4.z = b2f(Plds[w][row][l16*4+2]);
            o4.w = b2f(Plds[w][row][l16*4+3]);
            *(float4*)&ab[(size_t)(qr0+row)*SS + cbase + l16*4] = o4;
          }
        } else {
          f4 z = (f4){0.f,0.f,0.f,0.f};
          #pragma unroll
          for (int r4=0;r4<4;r4++){
            int row = r4*4 + lq;
            *(f4*)&ab[(size_t)(qr0+row)*SS + cbase + l16*4] = z;
          }
        }
      }
    }

    #pragma unroll
    for (int dt=0;dt<2;dt++){
      #pragma unroll
      for (int i=0;i<4;i++){
        int row = qr0 + lq*4 + i;
        ctx[((size_t)(b*SS + row))*H + h*DH + dt*16 + l16] = f2b(o[dt][i]*inv[i]);
      }
    }
  }
}

// -------------------------------------------------------------------------
__global__ __launch_bounds__(128) void logits_kernel(
    const u16* __restrict__ hid, const float* __restrict__ ow,
    const float* __restrict__ ob, float* __restrict__ out){
  int t = threadIdx.x;
  int b = t >> 2, a = t & 3;
  const u16* hr = hid + ((size_t)b*SS + (SS-1))*H;
  float acc = ob[a];
  for (int k2=0;k2<H;k2++) acc = fmaf(b2f(hr[k2]), ow[k2*AA + a], acc);
  out[t] = acc;
}

// -------------------------------------------------------------------------
extern "C" void kernel_launch(void* const* d_in, const int* in_sizes, int n_in,
                              void* d_out, int out_size, void* d_ws, size_t ws_size,
                              hipStream_t stream){
  (void)in_sizes; (void)n_in; (void)out_size; (void)ws_size;
  const float* x      = (const float*)d_in[0];
  const float* tf     = (const float*)d_in[1];
  const float* fp_w   = (const float*)d_in[2];
  const float* fp_b   = (const float*)d_in[3];
  const float* tp_w   = (const float*)d_in[4];
  const float* tp_b   = (const float*)d_in[5];
  const float* ip_w   = (const float*)d_in[6];
  const float* ip_b   = (const float*)d_in[7];
  const float* wq     = (const float*)d_in[8];
  const float* wk     = (const float*)d_in[9];
  const float* wv     = (const float*)d_in[10];
  const float* wo     = (const float*)d_in[11];
  const float* bq     = (const float*)d_in[12];
  const float* bk     = (const float*)d_in[13];
  const float* bv     = (const float*)d_in[14];
  const float* bo     = (const float*)d_in[15];
  const float* ln_g   = (const float*)d_in[16];
  const float* ln_b   = (const float*)d_in[17];
  const float* g_fc1w = (const float*)d_in[18];
  const float* g_fc2w = (const float*)d_in[19];
  const float* g_gw   = (const float*)d_in[20];
  const float* g_ggw  = (const float*)d_in[21];
  const float* g_fc1b = (const float*)d_in[22];
  const float* g_fc2b = (const float*)d_in[23];
  const float* g_gb   = (const float*)d_in[24];
  const float* g_ggb  = (const float*)d_in[25];
  const float* g_lg   = (const float*)d_in[26];
  const float* g_lb   = (const float*)d_in[27];
  const float* f_fc1w = (const float*)d_in[28];
  const float* f_fc2w = (const float*)d_in[29];
  const float* f_gw   = (const float*)d_in[30];
  const float* f_ggw  = (const float*)d_in[31];
  const float* f_fc1b = (const float*)d_in[32];
  const float* f_fc2b = (const float*)d_in[33];
  const float* f_gb   = (const float*)d_in[34];
  const float* f_ggb  = (const float*)d_in[35];
  const float* f_lg   = (const float*)d_in[36];
  const float* f_lb   = (const float*)d_in[37];
  const float* out_w  = (const float*)d_in[38];
  const float* out_b  = (const float*)d_in[39];

  float* logits = (float*)d_out;
  float* aw     = logits + BB*AA;

  // ws layout (u16): 21 transposed weights | Wcat | Abuf | hid | buf1..3
  u16* wts = (u16*)d_ws;
  const size_t WMAT = (size_t)H*H;
  u16* wcat = wts  + 21*WMAT;
  u16* abuf = wcat + (size_t)H*KIN;
  u16* hid  = abuf + (size_t)T_TOK*KIN;
  size_t BUF = (size_t)T_TOK * H;
  u16* buf1 = hid  + BUF;
  u16* buf2 = buf1 + BUF;
  u16* buf3 = buf2 + BUF;

  WPtrs wp;
  wp.p[0]  = ip_w;
  wp.p[1]  = wq;        wp.p[2]  = wq + WMAT;
  wp.p[3]  = wk;        wp.p[4]  = wk + WMAT;
  wp.p[5]  = wv;        wp.p[6]  = wv + WMAT;
  wp.p[7]  = wo;        wp.p[8]  = wo + WMAT;
  wp.p[9]  = g_fc1w;    wp.p[10] = g_fc1w + WMAT;
  wp.p[11] = g_fc2w;    wp.p[12] = g_fc2w + WMAT;
  wp.p[13] = g_gw;      wp.p[14] = g_gw + WMAT;
  wp.p[15] = g_ggw;     wp.p[16] = g_ggw + WMAT;
  wp.p[17] = f_fc1w;    wp.p[18] = f_fc2w;
  wp.p[19] = f_gw;      wp.p[20] = f_ggw;
  const int WT_IP=0, WT_Q=1, WT_K=3, WT_V=5, WT_O=7,
            WT_FC1=9, WT_FC2=11, WT_GW=13, WT_GGW=15,
            WT_FFC1=17, WT_FFC2=18, WT_FGW=19, WT_FGGW=20;

  dim3 b256(256), b512(512);
  dim3 gAttn(2, BB*NH);
  dim3 gTok(T_TOK/32);

  prep_kernel<<<336+224+14336, b256, 0, stream>>>(wp, wts, fp_w, tp_w, wcat, x, tf, abuf);
  input_kernel<<<gTok, b512, 0, stream>>>(abuf, wcat, fp_b, tp_b,
                                          wts + (size_t)WT_IP*WMAT, ip_b, hid);

  for (int i=0;i<LAYERS;i++){
    const size_t BOFF = (size_t)i*H;
    GemmBatch gb;
    gb.j[0] = { wts + (size_t)(WT_Q+i)*WMAT, bq+BOFF, buf1 };
    gb.j[1] = { wts + (size_t)(WT_K+i)*WMAT, bk+BOFF, buf2 };
    gb.j[2] = { wts + (size_t)(WT_V+i)*WMAT, bv+BOFF, buf3 };
    gemm_bf16<<<dim3(T_TOK/128, H/64, 3), b256, 0, stream>>>(hid, gb);
    if (i == LAYERS-1)
      attn_kernel<1><<<gAttn, b256, 0, stream>>>(buf1, buf2, buf3, aw, buf1);
    else
      attn_kernel<0><<<gAttn, b256, 0, stream>>>(buf1, buf2, buf3, aw, buf1);
    post_kernel<1><<<gTok, b512, 0, stream>>>(buf1, hid,
        wts + (size_t)(WT_O+i)*WMAT, bo+BOFF, ln_g+BOFF, ln_b+BOFF,
        wts + (size_t)(WT_FC1+i)*WMAT, wts + (size_t)(WT_FC2+i)*WMAT,
        wts + (size_t)(WT_GW+i)*WMAT,  wts + (size_t)(WT_GGW+i)*WMAT,
        g_fc1b+BOFF, g_fc2b+BOFF, g_gb+BOFF, g_ggb+BOFF,
        g_lg+BOFF, g_lb+BOFF);
  }

  post_kernel<0><<<gTok, b512, 0, stream>>>(nullptr, hid,
      nullptr, nullptr, nullptr, nullptr,
      wts + (size_t)WT_FFC1*WMAT, wts + (size_t)WT_FFC2*WMAT,
      wts + (size_t)WT_FGW*WMAT,  wts + (size_t)WT_FGGW*WMAT,
      f_fc1b, f_fc2b, f_gb, f_ggb, f_lg, f_lb);

  logits_kernel<<<1, 128, 0, stream>>>(hid, out_w, out_b, logits);
}